// Round 1
// baseline (147.496 us; speedup 1.0000x reference)
//
#include <hip/hip_runtime.h>
#include <cmath>

#define BB 64
#define TT 512
#define CC 1000
#define SS 32
#define COR 4
#define NPROB (BB + BB*COR)   // 320
#define NEGV (-1e30f)
#define LOG2E 1.4426950408889634f
#define LN2 0.6931471805599453f

// ---------------------------------------------------------------------------
// Kernel 1: lse[row] = logsumexp(preds[row, :]) for row in [0, B*T)
// One wave per row; float4-vectorized coalesced loads (1000 = 250 float4).
// ---------------------------------------------------------------------------
__global__ __launch_bounds__(256) void lse_kernel(const float* __restrict__ preds,
                                                  float* __restrict__ lse) {
    int wave = (blockIdx.x * blockDim.x + threadIdx.x) >> 6;
    int lane = threadIdx.x & 63;
    if (wave >= BB * TT) return;
    const float4* row = (const float4*)(preds + (size_t)wave * CC);
    float v[16];
#pragma unroll
    for (int i = 0; i < 4; ++i) {
        int idx = lane + i * 64;
        float4 x;
        if (idx < 250) x = row[idx];
        else x = make_float4(-INFINITY, -INFINITY, -INFINITY, -INFINITY);
        v[i*4+0] = x.x; v[i*4+1] = x.y; v[i*4+2] = x.z; v[i*4+3] = x.w;
    }
    float m = v[0];
#pragma unroll
    for (int i = 1; i < 16; ++i) m = fmaxf(m, v[i]);
#pragma unroll
    for (int off = 32; off; off >>= 1) m = fmaxf(m, __shfl_xor(m, off));
    float s = 0.f;
#pragma unroll
    for (int i = 0; i < 16; ++i) s += exp2f((v[i] - m) * LOG2E);
#pragma unroll
    for (int off = 32; off; off >>= 1) s += __shfl_xor(s, off);
    if (lane == 0) lse[wave] = m + log2f(s) * LN2;
}

// ---------------------------------------------------------------------------
// Kernel 2: one wave per CTC problem (64 master + 256 smooth).
// Lane s (0..63) owns alpha[s]; alpha[64] (blank) is maintained redundantly
// on all lanes. Recursion runs on RAW preds gathers (no per-step -lse):
// logaddexp is shift-invariant, so alpha_raw = alpha_true + K_t with
// K_t = sum_{t'<=t} lse_t'. Final loss = K - logaddexp(aT[idx], aT[idx-1]).
// Emit loads are alpha-independent -> double-buffered 8-step chunks.
// ---------------------------------------------------------------------------
__global__ __launch_bounds__(64) void ctc_kernel(const float* __restrict__ preds,
                                                 const float* __restrict__ lse,
                                                 const int* __restrict__ text,
                                                 const int* __restrict__ length,
                                                 const int* __restrict__ stext,
                                                 const int* __restrict__ slength,
                                                 float* __restrict__ lm,
                                                 float* __restrict__ ls) {
    const int p = blockIdx.x;
    const int lane = threadIdx.x;

    int b, len;
    const int* tgt;
    if (p < BB) { b = p;        tgt = text  + (size_t)p * SS; len = length[p]; }
    else { int i = p - BB; b = i / COR; tgt = stext + (size_t)i * SS; len = slength[i]; }

    // extended-label class for this lane's position s = lane
    const int s = lane;
    int cls = (s & 1) ? tgt[(s - 1) >> 1] : 0;
    bool use2 = false;                      // allow s-2 -> s skip transition
    if ((s & 1) && s >= 3) use2 = (cls != tgt[(s - 3) >> 1]);

    const float* pcls = preds + (size_t)b * TT * CC + cls;
    const float* lrow = lse + (size_t)b * TT;

    // K = sum_t lse[b,t]  (deterministic: strided partials + butterfly)
    float ksum = 0.f;
#pragma unroll
    for (int i = 0; i < TT / 64; ++i) ksum += lrow[lane + i * 64];
#pragma unroll
    for (int off = 32; off; off >>= 1) ksum += __shfl_xor(ksum, off);

    float a, a64;

    constexpr int CH = 8;
    constexpr int NCH = TT / CH;            // 64
    float pvA[CH], pvB[CH];

    auto loadChunk = [&](float (&pv)[CH], int c) {
#pragma unroll
        for (int j = 0; j < CH; ++j)
            pv[j] = pcls[(size_t)(c * CH + j) * CC];
    };

    auto step = [&](float ev) {
        float p1  = __shfl_up(a, 1);
        float p2  = __shfl_up(a, 2);
        float a63 = __shfl(a, 63);
        float eb  = __shfl(ev, 0);          // blank emit (lane 0's class is 0)
        float x1 = (lane >= 1) ? p1 : NEGV;
        float x2 = use2 ? p2 : NEGV;
        // 3-way logsumexp for positions 0..63
        float m3 = fmaxf(fmaxf(a, x1), x2);
        float ss = exp2f((a  - m3) * LOG2E)
                 + exp2f((x1 - m3) * LOG2E)
                 + exp2f((x2 - m3) * LOG2E);
        float anew = m3 + log2f(ss) * LN2 + ev;
        // position 64: blank, no skip -> logaddexp(a64, a63) + blank emit
        float m2 = fmaxf(a64, a63);
        float s2 = exp2f((a64 - m2) * LOG2E) + exp2f((a63 - m2) * LOG2E);
        a64 = m2 + log2f(s2) * LN2 + eb;
        a = anew;
    };

    // prologue: chunk 0 (t=0 is init), chunk 1 prefetched
    loadChunk(pvA, 0);
    loadChunk(pvB, 1);
    a = (s < 2) ? pvA[0] : NEGV;
    a64 = NEGV;
#pragma unroll
    for (int j = 1; j < CH; ++j) step(pvA[j]);

    // main loop: double-buffered, static indexing only
    for (int c = 1; c < NCH; c += 2) {
        if (c + 1 < NCH) loadChunk(pvA, c + 1);
#pragma unroll
        for (int j = 0; j < CH; ++j) step(pvB[j]);
        if (c + 1 < NCH) {
            if (c + 2 < NCH) loadChunk(pvB, c + 2);
#pragma unroll
            for (int j = 0; j < CH; ++j) step(pvA[j]);
        }
    }

    // extract: loss = K - logaddexp(alphaT[2*len], alphaT[2*len-1])
    int idx = 2 * len;                       // in [16, 64]
    float av  = __shfl(a, idx & 63);
    float vhi = (idx < 64) ? av : a64;
    float vlo = __shfl(a, idx - 1);
    float mm = fmaxf(vhi, vlo);
    float lae = mm + log2f(exp2f((vhi - mm) * LOG2E) + exp2f((vlo - mm) * LOG2E)) * LN2;
    float loss = ksum - lae;

    if (lane == 0) {
        if (p < BB) lm[p] = loss;
        else        ls[p - BB] = loss;
    }
}

// ---------------------------------------------------------------------------
// Kernel 3: finalize scalar loss.
// ---------------------------------------------------------------------------
__global__ __launch_bounds__(256) void fin_kernel(const float* __restrict__ lm,
                                                  const float* __restrict__ ls,
                                                  const int* __restrict__ length,
                                                  const int* __restrict__ slength,
                                                  float* __restrict__ out) {
    __shared__ float red[256];
    const int tid = threadIdx.x;

    float mterm = 0.f;
    if (tid < BB) mterm = lm[tid] / (float)length[tid];

    int bb = tid >> 2;                       // ranking index (repeat by COR)
    float conf = expf(-lm[bb]);
    float r = 0.01f + 0.99f * (1.f - conf) * (1.f - conf);
    int sl = slength[tid]; if (sl < 1) sl = 1;
    float sterm = r * ls[tid] / (float)sl;

    red[tid] = mterm; __syncthreads();
    for (int off = 128; off; off >>= 1) {
        if (tid < off) red[tid] += red[tid + off];
        __syncthreads();
    }
    float sum_m = red[0];
    __syncthreads();

    red[tid] = sterm; __syncthreads();
    for (int off = 128; off; off >>= 1) {
        if (tid < off) red[tid] += red[tid + off];
        __syncthreads();
    }
    if (tid == 0)
        out[0] = sum_m / (float)BB + 0.1f * (red[0] / (float)(BB * COR));
}

// ---------------------------------------------------------------------------
extern "C" void kernel_launch(void* const* d_in, const int* in_sizes, int n_in,
                              void* d_out, int out_size, void* d_ws, size_t ws_size,
                              hipStream_t stream) {
    const float* preds   = (const float*)d_in[0];
    const int*   text    = (const int*)d_in[1];
    const int*   length  = (const int*)d_in[2];
    const int*   stext   = (const int*)d_in[3];
    const int*   slength = (const int*)d_in[4];
    float* out = (float*)d_out;

    float* lse = (float*)d_ws;               // B*T = 32768 floats
    float* lm  = lse + BB * TT;              // 64 floats
    float* ls  = lm + BB;                    // 256 floats

    lse_kernel<<<(BB * TT) / 4, 256, 0, stream>>>(preds, lse);
    ctc_kernel<<<NPROB, 64, 0, stream>>>(preds, lse, text, length, stext, slength, lm, ls);
    fin_kernel<<<1, 256, 0, stream>>>(lm, ls, length, slength, out);
}

// Round 2
// 139.901 us; speedup vs baseline: 1.0543x; 1.0543x over previous
//
#include <hip/hip_runtime.h>
#include <cmath>

#define BB 64
#define TT 512
#define CC 1000
#define SS 32
#define COR 4
#define NPROB (BB + BB*COR)   // 320
#define NEGV (-1e30f)
#define LOG2E 1.4426950408889634f
#define LN2 0.6931471805599453f

// ---------------------------------------------------------------------------
// Fused kernel: per preds row [b,t,:]:
//   - coalesced float4 read of all 1000 classes (scaled to log2-domain)
//   - lse2[b,t] = log2(sum exp) via wave butterfly
//   - gather the 160 label emits (5 problems x 32 labels) + blank emit into a
//     DENSE layout: labels[pid][t][k] (pid: 0..63 master, 64..319 smooth),
//     blank[b][t]. Gathers hit L1/L2 (row was just streamed through).
// ---------------------------------------------------------------------------
__global__ __launch_bounds__(256) void gather_kernel(const float* __restrict__ preds,
                                                     const int* __restrict__ text,
                                                     const int* __restrict__ stext,
                                                     float* __restrict__ lse2,
                                                     float* __restrict__ labels,
                                                     float* __restrict__ blankv) {
    int gw = (blockIdx.x * blockDim.x + threadIdx.x) >> 6;   // row = b*512+t
    int lane = threadIdx.x & 63;
    if (gw >= BB * TT) return;
    int b = gw >> 9;
    int t = gw & (TT - 1);
    const float* row = preds + (size_t)gw * CC;
    const float4* row4 = (const float4*)row;
    float w[16];
#pragma unroll
    for (int i = 0; i < 4; ++i) {
        int idx = lane + i * 64;
        float4 x = (idx < 250) ? row4[idx] : make_float4(NEGV, NEGV, NEGV, NEGV);
        w[i*4+0] = x.x * LOG2E; w[i*4+1] = x.y * LOG2E;
        w[i*4+2] = x.z * LOG2E; w[i*4+3] = x.w * LOG2E;
    }
    float m = w[0];
#pragma unroll
    for (int i = 1; i < 16; ++i) m = fmaxf(m, w[i]);
#pragma unroll
    for (int off = 32; off; off >>= 1) m = fmaxf(m, __shfl_xor(m, off));
    float s = 0.f;
#pragma unroll
    for (int i = 0; i < 16; ++i) s += exp2f(w[i] - m);
#pragma unroll
    for (int off = 32; off; off >>= 1) s += __shfl_xor(s, off);
    if (lane == 0) { lse2[gw] = m + log2f(s); blankv[gw] = row[0] * LOG2E; }

    // gather 5*32 = 160 label emits
#pragma unroll
    for (int it = 0; it < 3; ++it) {
        int g = lane + it * 64;
        if (g < 5 * SS) {
            int pp = g >> 5, k = g & 31;
            int cls, pid;
            if (pp == 0) { cls = text[b * SS + k]; pid = b; }
            else { int i = b * COR + (pp - 1); cls = stext[i * SS + k]; pid = BB + i; }
            labels[((size_t)pid * TT + t) * SS + k] = row[cls] * LOG2E;
        }
    }
}

// ---------------------------------------------------------------------------
// Dense CTC: one wave per problem. Lane s owns alpha[s] (log2 domain, raw
// preds — shift-invariance: loss = ln2*(sum_t lse2 - logadd2(aT[idx],aT[idx-1])).
// Odd lane s streams labels[p][t][(s-1)/2]; even lanes broadcast the blank
// stream. a64 (position 64) is maintained only when len==32 (template FULL).
// ---------------------------------------------------------------------------
template<bool FULL>
__device__ __forceinline__ float ctc_run(const float* __restrict__ base, int stride,
                                         int lane, bool use2, int idx) {
    float a, a64 = NEGV;
    constexpr int CH = 8;
    constexpr int NCH = TT / CH;            // 64
    float pvA[CH], pvB[CH];

    auto loadChunk = [&](float (&pv)[CH], int c) {
#pragma unroll
        for (int j = 0; j < CH; ++j) pv[j] = base[(size_t)(c * CH + j) * stride];
    };

    auto step = [&](float ev) {
        float p1 = __shfl_up(a, 1);
        float p2 = __shfl_up(a, 2);
        float x1 = (lane >= 1) ? p1 : NEGV;
        float x2 = use2 ? p2 : NEGV;
        float m3 = fmaxf(fmaxf(a, x1), x2);
        float ss = exp2f(a - m3) + exp2f(x1 - m3) + exp2f(x2 - m3);
        float anew = m3 + log2f(ss) + ev;
        if (FULL) {
            float a63 = __shfl(a, 63);
            float eb  = __shfl(ev, 0);
            float m2 = fmaxf(a64, a63);
            a64 = m2 + log2f(exp2f(a64 - m2) + exp2f(a63 - m2)) + eb;
        }
        a = anew;
    };

    loadChunk(pvA, 0);
    loadChunk(pvB, 1);
    a = (lane < 2) ? pvA[0] : NEGV;
#pragma unroll
    for (int j = 1; j < CH; ++j) step(pvA[j]);

    for (int c = 1; c < NCH; c += 2) {
        if (c + 1 < NCH) loadChunk(pvA, c + 1);
#pragma unroll
        for (int j = 0; j < CH; ++j) step(pvB[j]);
        if (c + 1 < NCH) {
            if (c + 2 < NCH) loadChunk(pvB, c + 2);
#pragma unroll
            for (int j = 0; j < CH; ++j) step(pvA[j]);
        }
    }

    float vlo = __shfl(a, (idx - 1) & 63);
    float vhi = FULL ? a64 : __shfl(a, idx & 63);
    float mm = fmaxf(vhi, vlo);
    return mm + log2f(exp2f(vhi - mm) + exp2f(vlo - mm));
}

__global__ __launch_bounds__(64) void ctc_dense_kernel(const float* __restrict__ labels,
                                                       const float* __restrict__ blankv,
                                                       const float* __restrict__ lse2,
                                                       const int* __restrict__ text,
                                                       const int* __restrict__ length,
                                                       const int* __restrict__ stext,
                                                       const int* __restrict__ slength,
                                                       float* __restrict__ lm,
                                                       float* __restrict__ ls) {
    const int p = blockIdx.x;
    const int lane = threadIdx.x;

    int b, len;
    const int* tgt;
    if (p < BB) { b = p;        tgt = text  + (size_t)p * SS; len = length[p]; }
    else { int i = p - BB; b = i / COR; tgt = stext + (size_t)i * SS; len = slength[i]; }

    bool odd = lane & 1;
    int k = (lane - 1) >> 1;
    bool use2 = false;
    if (odd && lane >= 3) use2 = (tgt[k] != tgt[k - 1]);

    const float* base; int stride;
    if (odd) { base = labels + (size_t)p * TT * SS + k; stride = SS; }
    else     { base = blankv + (size_t)b * TT;          stride = 1;  }

    // ksum2 = sum_t lse2[b,t]
    const float* lrow = lse2 + (size_t)b * TT;
    float ksum = 0.f;
#pragma unroll
    for (int i = 0; i < TT / 64; ++i) ksum += lrow[lane + i * 64];
#pragma unroll
    for (int off = 32; off; off >>= 1) ksum += __shfl_xor(ksum, off);

    int idx = 2 * len;
    float lae2 = (len == SS) ? ctc_run<true >(base, stride, lane, use2, idx)
                             : ctc_run<false>(base, stride, lane, use2, idx);
    float loss = LN2 * (ksum - lae2);

    if (lane == 0) {
        if (p < BB) lm[p] = loss;
        else        ls[p - BB] = loss;
    }
}

// ---------------------------------------------------------------------------
// Fallback path (round-1, used only if ws_size is too small for dense emit)
// ---------------------------------------------------------------------------
__global__ __launch_bounds__(256) void lse_kernel(const float* __restrict__ preds,
                                                  float* __restrict__ lse) {
    int wave = (blockIdx.x * blockDim.x + threadIdx.x) >> 6;
    int lane = threadIdx.x & 63;
    if (wave >= BB * TT) return;
    const float4* row = (const float4*)(preds + (size_t)wave * CC);
    float v[16];
#pragma unroll
    for (int i = 0; i < 4; ++i) {
        int idx = lane + i * 64;
        float4 x = (idx < 250) ? row[idx] : make_float4(NEGV, NEGV, NEGV, NEGV);
        v[i*4+0] = x.x; v[i*4+1] = x.y; v[i*4+2] = x.z; v[i*4+3] = x.w;
    }
    float m = v[0];
#pragma unroll
    for (int i = 1; i < 16; ++i) m = fmaxf(m, v[i]);
#pragma unroll
    for (int off = 32; off; off >>= 1) m = fmaxf(m, __shfl_xor(m, off));
    float s = 0.f;
#pragma unroll
    for (int i = 0; i < 16; ++i) s += exp2f((v[i] - m) * LOG2E);
#pragma unroll
    for (int off = 32; off; off >>= 1) s += __shfl_xor(s, off);
    if (lane == 0) lse[wave] = m + log2f(s) * LN2;
}

__global__ __launch_bounds__(64) void ctc_kernel(const float* __restrict__ preds,
                                                 const float* __restrict__ lse,
                                                 const int* __restrict__ text,
                                                 const int* __restrict__ length,
                                                 const int* __restrict__ stext,
                                                 const int* __restrict__ slength,
                                                 float* __restrict__ lm,
                                                 float* __restrict__ ls) {
    const int p = blockIdx.x;
    const int lane = threadIdx.x;
    int b, len;
    const int* tgt;
    if (p < BB) { b = p;        tgt = text  + (size_t)p * SS; len = length[p]; }
    else { int i = p - BB; b = i / COR; tgt = stext + (size_t)i * SS; len = slength[i]; }
    const int s = lane;
    int cls = (s & 1) ? tgt[(s - 1) >> 1] : 0;
    bool use2 = false;
    if ((s & 1) && s >= 3) use2 = (cls != tgt[(s - 3) >> 1]);
    const float* pcls = preds + (size_t)b * TT * CC + cls;
    const float* lrow = lse + (size_t)b * TT;
    float ksum = 0.f;
#pragma unroll
    for (int i = 0; i < TT / 64; ++i) ksum += lrow[lane + i * 64];
#pragma unroll
    for (int off = 32; off; off >>= 1) ksum += __shfl_xor(ksum, off);
    float a, a64;
    constexpr int CH = 8;
    constexpr int NCH = TT / CH;
    float pvA[CH], pvB[CH];
    auto loadChunk = [&](float (&pv)[CH], int c) {
#pragma unroll
        for (int j = 0; j < CH; ++j) pv[j] = pcls[(size_t)(c * CH + j) * CC];
    };
    auto step = [&](float ev) {
        float p1  = __shfl_up(a, 1);
        float p2  = __shfl_up(a, 2);
        float a63 = __shfl(a, 63);
        float eb  = __shfl(ev, 0);
        float x1 = (lane >= 1) ? p1 : NEGV;
        float x2 = use2 ? p2 : NEGV;
        float m3 = fmaxf(fmaxf(a, x1), x2);
        float ss = exp2f((a  - m3) * LOG2E) + exp2f((x1 - m3) * LOG2E) + exp2f((x2 - m3) * LOG2E);
        float anew = m3 + log2f(ss) * LN2 + ev;
        float m2 = fmaxf(a64, a63);
        float s2 = exp2f((a64 - m2) * LOG2E) + exp2f((a63 - m2) * LOG2E);
        a64 = m2 + log2f(s2) * LN2 + eb;
        a = anew;
    };
    loadChunk(pvA, 0);
    loadChunk(pvB, 1);
    a = (s < 2) ? pvA[0] : NEGV;
    a64 = NEGV;
#pragma unroll
    for (int j = 1; j < CH; ++j) step(pvA[j]);
    for (int c = 1; c < NCH; c += 2) {
        if (c + 1 < NCH) loadChunk(pvA, c + 1);
#pragma unroll
        for (int j = 0; j < CH; ++j) step(pvB[j]);
        if (c + 1 < NCH) {
            if (c + 2 < NCH) loadChunk(pvB, c + 2);
#pragma unroll
            for (int j = 0; j < CH; ++j) step(pvA[j]);
        }
    }
    int idx = 2 * len;
    float av  = __shfl(a, idx & 63);
    float vhi = (idx < 64) ? av : a64;
    float vlo = __shfl(a, idx - 1);
    float mm = fmaxf(vhi, vlo);
    float lae = mm + log2f(exp2f((vhi - mm) * LOG2E) + exp2f((vlo - mm) * LOG2E)) * LN2;
    float loss = ksum - lae;
    if (lane == 0) {
        if (p < BB) lm[p] = loss;
        else        ls[p - BB] = loss;
    }
}

// ---------------------------------------------------------------------------
// Finalize scalar loss.
// ---------------------------------------------------------------------------
__global__ __launch_bounds__(256) void fin_kernel(const float* __restrict__ lm,
                                                  const float* __restrict__ ls,
                                                  const int* __restrict__ length,
                                                  const int* __restrict__ slength,
                                                  float* __restrict__ out) {
    __shared__ float red[256];
    const int tid = threadIdx.x;

    float mterm = 0.f;
    if (tid < BB) mterm = lm[tid] / (float)length[tid];

    int bb = tid >> 2;
    float conf = expf(-lm[bb]);
    float r = 0.01f + 0.99f * (1.f - conf) * (1.f - conf);
    int sl = slength[tid]; if (sl < 1) sl = 1;
    float sterm = r * ls[tid] / (float)sl;

    red[tid] = mterm; __syncthreads();
    for (int off = 128; off; off >>= 1) {
        if (tid < off) red[tid] += red[tid + off];
        __syncthreads();
    }
    float sum_m = red[0];
    __syncthreads();

    red[tid] = sterm; __syncthreads();
    for (int off = 128; off; off >>= 1) {
        if (tid < off) red[tid] += red[tid + off];
        __syncthreads();
    }
    if (tid == 0)
        out[0] = sum_m / (float)BB + 0.1f * (red[0] / (float)(BB * COR));
}

// ---------------------------------------------------------------------------
extern "C" void kernel_launch(void* const* d_in, const int* in_sizes, int n_in,
                              void* d_out, int out_size, void* d_ws, size_t ws_size,
                              hipStream_t stream) {
    const float* preds   = (const float*)d_in[0];
    const int*   text    = (const int*)d_in[1];
    const int*   length  = (const int*)d_in[2];
    const int*   stext   = (const int*)d_in[3];
    const int*   slength = (const int*)d_in[4];
    float* out = (float*)d_out;

    size_t need = ((size_t)BB * TT * 2 + BB + BB * COR + (size_t)NPROB * TT * SS) * sizeof(float);

    if (ws_size >= need) {
        float* lse2   = (float*)d_ws;            // 32768
        float* blankv = lse2 + BB * TT;          // 32768
        float* lm     = blankv + BB * TT;        // 64
        float* ls     = lm + BB;                 // 256
        float* labels = ls + BB * COR;           // 320*512*32

        gather_kernel<<<(BB * TT) / 4, 256, 0, stream>>>(preds, text, stext, lse2, labels, blankv);
        ctc_dense_kernel<<<NPROB, 64, 0, stream>>>(labels, blankv, lse2, text, length, stext, slength, lm, ls);
        fin_kernel<<<1, 256, 0, stream>>>(lm, ls, length, slength, out);
    } else {
        float* lse = (float*)d_ws;
        float* lm  = lse + BB * TT;
        float* ls  = lm + BB;
        lse_kernel<<<(BB * TT) / 4, 256, 0, stream>>>(preds, lse);
        ctc_kernel<<<NPROB, 64, 0, stream>>>(preds, lse, text, length, stext, slength, lm, ls);
        fin_kernel<<<1, 256, 0, stream>>>(lm, ls, length, slength, out);
    }
}

// Round 3
// 114.171 us; speedup vs baseline: 1.2919x; 1.2254x over previous
//
#include <hip/hip_runtime.h>
#include <cmath>

#define BB 64
#define TT 512
#define CC 1000
#define SS 32
#define COR 4
#define NPROB (BB + BB*COR)   // 320
#define NEGV (-1e30f)
#define LOG2E 1.4426950408889634f
#define LN2 0.6931471805599453f

// ---------------------------------------------------------------------------
// wave_shr1 via DPP (dpp_ctrl 0x138): lane i <- lane i-1, lane 0 <- `fill`
// (bound_ctrl=false keeps the `old` operand on invalid lanes).
// VALU-pipe cross-lane: ~2cy vs ~100cy ds_bpermute — this is the whole point.
// ---------------------------------------------------------------------------
__device__ __forceinline__ float dpp_shr1(float x, float fill) {
    int xi = __builtin_bit_cast(int, x);
    int fi = __builtin_bit_cast(int, fill);
    int r = __builtin_amdgcn_update_dpp(fi, xi, 0x138, 0xf, 0xf, false);
    return __builtin_bit_cast(float, r);
}

__device__ __forceinline__ float rdlane(float x, int lane) {
    return __builtin_bit_cast(float, __builtin_amdgcn_readlane(__builtin_bit_cast(int, x), lane));
}

// ---------------------------------------------------------------------------
// Fused kernel: per preds row [b,t,:]:
//   coalesced float4 read, log2-domain lse via butterfly, and dense scatter of
//   the 160 label emits + blank emit (gathers hit L1 -- row just streamed).
// ---------------------------------------------------------------------------
__global__ __launch_bounds__(256) void gather_kernel(const float* __restrict__ preds,
                                                     const int* __restrict__ text,
                                                     const int* __restrict__ stext,
                                                     float* __restrict__ lse2,
                                                     float* __restrict__ labels,
                                                     float* __restrict__ blankv) {
    int gw = (blockIdx.x * blockDim.x + threadIdx.x) >> 6;   // row = b*512+t
    int lane = threadIdx.x & 63;
    if (gw >= BB * TT) return;
    int b = gw >> 9;
    int t = gw & (TT - 1);
    const float* row = preds + (size_t)gw * CC;
    const float4* row4 = (const float4*)row;
    float w[16];
#pragma unroll
    for (int i = 0; i < 4; ++i) {
        int idx = lane + i * 64;
        float4 x = (idx < 250) ? row4[idx] : make_float4(NEGV, NEGV, NEGV, NEGV);
        w[i*4+0] = x.x * LOG2E; w[i*4+1] = x.y * LOG2E;
        w[i*4+2] = x.z * LOG2E; w[i*4+3] = x.w * LOG2E;
    }
    float m = w[0];
#pragma unroll
    for (int i = 1; i < 16; ++i) m = fmaxf(m, w[i]);
#pragma unroll
    for (int off = 32; off; off >>= 1) m = fmaxf(m, __shfl_xor(m, off));
    float s = 0.f;
#pragma unroll
    for (int i = 0; i < 16; ++i) s += exp2f(w[i] - m);
#pragma unroll
    for (int off = 32; off; off >>= 1) s += __shfl_xor(s, off);
    if (lane == 0) { lse2[gw] = m + log2f(s); blankv[gw] = row[0] * LOG2E; }

#pragma unroll
    for (int it = 0; it < 3; ++it) {
        int g = lane + it * 64;
        if (g < 5 * SS) {
            int pp = g >> 5, k = g & 31;
            int cls, pid;
            if (pp == 0) { cls = text[b * SS + k]; pid = b; }
            else { int i = b * COR + (pp - 1); cls = stext[i * SS + k]; pid = BB + i; }
            labels[((size_t)pid * TT + t) * SS + k] = row[cls] * LOG2E;
        }
    }
}

// ---------------------------------------------------------------------------
// Dense CTC, DPP edition. Lane s owns alpha[s] (log2 domain, raw emits).
// Per-step chain is pure VALU: 2x dpp wave_shr1 + max3 + 3 exp2 + log2.
// Position 64 (only needed when len==32) via v_readlane, off the main chain.
// ---------------------------------------------------------------------------
template<bool FULL>
__device__ __forceinline__ float ctc_run(const float* __restrict__ base, int stride,
                                         int lane, bool use2, int idx) {
    float a, a64 = NEGV;
    constexpr int CH = 16;
    constexpr int NCH = TT / CH;            // 32
    float pvA[CH], pvB[CH];

    auto loadChunk = [&](float (&pv)[CH], int c) {
#pragma unroll
        for (int j = 0; j < CH; ++j) pv[j] = base[(size_t)(c * CH + j) * stride];
    };

    auto step = [&](float ev) {
        float p1 = dpp_shr1(a, NEGV);       // lane0 -> NEGV: boundary for free
        float p2 = dpp_shr1(p1, NEGV);
        float x2 = use2 ? p2 : NEGV;
        float m3 = fmaxf(fmaxf(a, p1), x2);
        float ss = exp2f(a - m3) + exp2f(p1 - m3) + exp2f(x2 - m3);
        if (FULL) {
            float a63 = rdlane(a, 63);
            float eb  = rdlane(ev, 0);
            float m2 = fmaxf(a64, a63);
            a64 = m2 + log2f(exp2f(a64 - m2) + exp2f(a63 - m2)) + eb;
        }
        a = m3 + log2f(ss) + ev;
    };

    loadChunk(pvA, 0);
    loadChunk(pvB, 1);
    a = (lane < 2) ? pvA[0] : NEGV;
#pragma unroll
    for (int j = 1; j < CH; ++j) step(pvA[j]);

    for (int c = 1; c < NCH; c += 2) {
        if (c + 1 < NCH) loadChunk(pvA, c + 1);
#pragma unroll
        for (int j = 0; j < CH; ++j) step(pvB[j]);
        if (c + 1 < NCH) {
            if (c + 2 < NCH) loadChunk(pvB, c + 2);
#pragma unroll
            for (int j = 0; j < CH; ++j) step(pvA[j]);
        }
    }

    float vlo = rdlane(a, idx - 1);
    float vhi = FULL ? a64 : rdlane(a, idx);
    float mm = fmaxf(vhi, vlo);
    return mm + log2f(exp2f(vhi - mm) + exp2f(vlo - mm));
}

__global__ __launch_bounds__(64) void ctc_dense_kernel(const float* __restrict__ labels,
                                                       const float* __restrict__ blankv,
                                                       const float* __restrict__ lse2,
                                                       const int* __restrict__ text,
                                                       const int* __restrict__ length,
                                                       const int* __restrict__ stext,
                                                       const int* __restrict__ slength,
                                                       float* __restrict__ lm,
                                                       float* __restrict__ ls) {
    const int p = blockIdx.x;
    const int lane = threadIdx.x;

    int b, len;
    const int* tgt;
    if (p < BB) { b = p;        tgt = text  + (size_t)p * SS; len = length[p]; }
    else { int i = p - BB; b = i / COR; tgt = stext + (size_t)i * SS; len = slength[i]; }

    bool odd = lane & 1;
    int k = (lane - 1) >> 1;
    bool use2 = false;
    if (odd && lane >= 3) use2 = (tgt[k] != tgt[k - 1]);

    const float* base; int stride;
    if (odd) { base = labels + (size_t)p * TT * SS + k; stride = SS; }
    else     { base = blankv + (size_t)b * TT;          stride = 1;  }

    const float* lrow = lse2 + (size_t)b * TT;
    float ksum = 0.f;
#pragma unroll
    for (int i = 0; i < TT / 64; ++i) ksum += lrow[lane + i * 64];
#pragma unroll
    for (int off = 32; off; off >>= 1) ksum += __shfl_xor(ksum, off);

    int idx = 2 * len;
    float lae2 = (len == SS) ? ctc_run<true >(base, stride, lane, use2, idx)
                             : ctc_run<false>(base, stride, lane, use2, idx);
    float loss = LN2 * (ksum - lae2);

    if (lane == 0) {
        if (p < BB) lm[p] = loss;
        else        ls[p - BB] = loss;
    }
}

// ---------------------------------------------------------------------------
// Fallback path (only if ws_size too small for dense emit) — round-1 kernels.
// ---------------------------------------------------------------------------
__global__ __launch_bounds__(256) void lse_kernel(const float* __restrict__ preds,
                                                  float* __restrict__ lse) {
    int wave = (blockIdx.x * blockDim.x + threadIdx.x) >> 6;
    int lane = threadIdx.x & 63;
    if (wave >= BB * TT) return;
    const float4* row = (const float4*)(preds + (size_t)wave * CC);
    float v[16];
#pragma unroll
    for (int i = 0; i < 4; ++i) {
        int idx = lane + i * 64;
        float4 x = (idx < 250) ? row[idx] : make_float4(NEGV, NEGV, NEGV, NEGV);
        v[i*4+0] = x.x; v[i*4+1] = x.y; v[i*4+2] = x.z; v[i*4+3] = x.w;
    }
    float m = v[0];
#pragma unroll
    for (int i = 1; i < 16; ++i) m = fmaxf(m, v[i]);
#pragma unroll
    for (int off = 32; off; off >>= 1) m = fmaxf(m, __shfl_xor(m, off));
    float s = 0.f;
#pragma unroll
    for (int i = 0; i < 16; ++i) s += exp2f((v[i] - m) * LOG2E);
#pragma unroll
    for (int off = 32; off; off >>= 1) s += __shfl_xor(s, off);
    if (lane == 0) lse[wave] = m + log2f(s) * LN2;
}

__global__ __launch_bounds__(64) void ctc_kernel(const float* __restrict__ preds,
                                                 const float* __restrict__ lse,
                                                 const int* __restrict__ text,
                                                 const int* __restrict__ length,
                                                 const int* __restrict__ stext,
                                                 const int* __restrict__ slength,
                                                 float* __restrict__ lm,
                                                 float* __restrict__ ls) {
    const int p = blockIdx.x;
    const int lane = threadIdx.x;
    int b, len;
    const int* tgt;
    if (p < BB) { b = p;        tgt = text  + (size_t)p * SS; len = length[p]; }
    else { int i = p - BB; b = i / COR; tgt = stext + (size_t)i * SS; len = slength[i]; }
    const int s = lane;
    int cls = (s & 1) ? tgt[(s - 1) >> 1] : 0;
    bool use2 = false;
    if ((s & 1) && s >= 3) use2 = (cls != tgt[(s - 3) >> 1]);
    const float* pcls = preds + (size_t)b * TT * CC + cls;
    const float* lrow = lse + (size_t)b * TT;
    float ksum = 0.f;
#pragma unroll
    for (int i = 0; i < TT / 64; ++i) ksum += lrow[lane + i * 64];
#pragma unroll
    for (int off = 32; off; off >>= 1) ksum += __shfl_xor(ksum, off);
    float a, a64 = NEGV;
    constexpr int CH = 8;
    constexpr int NCH = TT / CH;
    float pvA[CH], pvB[CH];
    auto loadChunk = [&](float (&pv)[CH], int c) {
#pragma unroll
        for (int j = 0; j < CH; ++j) pv[j] = pcls[(size_t)(c * CH + j) * CC];
    };
    auto step = [&](float ev) {
        float p1 = dpp_shr1(a, NEGV);
        float p2 = dpp_shr1(p1, NEGV);
        float x2 = use2 ? p2 : NEGV;
        float m3 = fmaxf(fmaxf(a, p1), x2);
        float ss = exp2f((a - m3) * LOG2E) + exp2f((p1 - m3) * LOG2E) + exp2f((x2 - m3) * LOG2E);
        float a63 = rdlane(a, 63);
        float eb  = rdlane(ev, 0);
        float m2 = fmaxf(a64, a63);
        a64 = m2 + log2f(exp2f((a64 - m2) * LOG2E) + exp2f((a63 - m2) * LOG2E)) * LN2 + eb;
        a = m3 + log2f(ss) * LN2 + ev;
    };
    loadChunk(pvA, 0);
    loadChunk(pvB, 1);
    a = (s < 2) ? pvA[0] : NEGV;
#pragma unroll
    for (int j = 1; j < CH; ++j) step(pvA[j]);
    for (int c = 1; c < NCH; c += 2) {
        if (c + 1 < NCH) loadChunk(pvA, c + 1);
#pragma unroll
        for (int j = 0; j < CH; ++j) step(pvB[j]);
        if (c + 1 < NCH) {
            if (c + 2 < NCH) loadChunk(pvB, c + 2);
#pragma unroll
            for (int j = 0; j < CH; ++j) step(pvA[j]);
        }
    }
    int idx = 2 * len;
    float vhi = (idx < 64) ? rdlane(a, idx) : a64;
    float vlo = rdlane(a, idx - 1);
    float mm = fmaxf(vhi, vlo);
    float lae = mm + log2f(exp2f((vhi - mm) * LOG2E) + exp2f((vlo - mm) * LOG2E)) * LN2;
    float loss = ksum - lae;
    if (lane == 0) {
        if (p < BB) lm[p] = loss;
        else        ls[p - BB] = loss;
    }
}

// ---------------------------------------------------------------------------
// Finalize scalar loss.
// ---------------------------------------------------------------------------
__global__ __launch_bounds__(256) void fin_kernel(const float* __restrict__ lm,
                                                  const float* __restrict__ ls,
                                                  const int* __restrict__ length,
                                                  const int* __restrict__ slength,
                                                  float* __restrict__ out) {
    __shared__ float red[256];
    const int tid = threadIdx.x;

    float mterm = 0.f;
    if (tid < BB) mterm = lm[tid] / (float)length[tid];

    int bb = tid >> 2;
    float conf = expf(-lm[bb]);
    float r = 0.01f + 0.99f * (1.f - conf) * (1.f - conf);
    int sl = slength[tid]; if (sl < 1) sl = 1;
    float sterm = r * ls[tid] / (float)sl;

    red[tid] = mterm; __syncthreads();
    for (int off = 128; off; off >>= 1) {
        if (tid < off) red[tid] += red[tid + off];
        __syncthreads();
    }
    float sum_m = red[0];
    __syncthreads();

    red[tid] = sterm; __syncthreads();
    for (int off = 128; off; off >>= 1) {
        if (tid < off) red[tid] += red[tid + off];
        __syncthreads();
    }
    if (tid == 0)
        out[0] = sum_m / (float)BB + 0.1f * (red[0] / (float)(BB * COR));
}

// ---------------------------------------------------------------------------
extern "C" void kernel_launch(void* const* d_in, const int* in_sizes, int n_in,
                              void* d_out, int out_size, void* d_ws, size_t ws_size,
                              hipStream_t stream) {
    const float* preds   = (const float*)d_in[0];
    const int*   text    = (const int*)d_in[1];
    const int*   length  = (const int*)d_in[2];
    const int*   stext   = (const int*)d_in[3];
    const int*   slength = (const int*)d_in[4];
    float* out = (float*)d_out;

    size_t need = ((size_t)BB * TT * 2 + BB + BB * COR + (size_t)NPROB * TT * SS) * sizeof(float);

    if (ws_size >= need) {
        float* lse2   = (float*)d_ws;            // 32768
        float* blankv = lse2 + BB * TT;          // 32768
        float* lm     = blankv + BB * TT;        // 64
        float* ls     = lm + BB;                 // 256
        float* labels = ls + BB * COR;           // 320*512*32

        gather_kernel<<<(BB * TT) / 4, 256, 0, stream>>>(preds, text, stext, lse2, labels, blankv);
        ctc_dense_kernel<<<NPROB, 64, 0, stream>>>(labels, blankv, lse2, text, length, stext, slength, lm, ls);
        fin_kernel<<<1, 256, 0, stream>>>(lm, ls, length, slength, out);
    } else {
        float* lse = (float*)d_ws;
        float* lm  = lse + BB * TT;
        float* ls  = lm + BB;
        lse_kernel<<<(BB * TT) / 4, 256, 0, stream>>>(preds, lse);
        ctc_kernel<<<NPROB, 64, 0, stream>>>(preds, lse, text, length, stext, slength, lm, ls);
        fin_kernel<<<1, 256, 0, stream>>>(lm, ls, length, slength, out);
    }
}

// Round 5
// 77.206 us; speedup vs baseline: 1.9104x; 1.4788x over previous
//
#include <hip/hip_runtime.h>
#include <cmath>

#define BB 64
#define TT 512
#define CC 1000
#define SS 32
#define COR 4
#define NPROB (BB + BB*COR)   // 320
#define NEGV (-1e30f)
#define LOG2E 1.4426950408889634f
#define LN2 0.6931471805599453f

// ---------------------------------------------------------------------------
// DPP wave_shr:1 (0x138) — verified on this HW in round 3 (absmax 0.0).
// ---------------------------------------------------------------------------
__device__ __forceinline__ float dpp_shr1_fill(float x, float fill) {
    int r = __builtin_amdgcn_update_dpp(__builtin_bit_cast(int, fill),
                                        __builtin_bit_cast(int, x),
                                        0x138, 0xf, 0xf, false);   // lane0 <- fill
    return __builtin_bit_cast(float, r);
}
__device__ __forceinline__ float dpp_shr1_z(float x) {
    int r = __builtin_amdgcn_update_dpp(0, __builtin_bit_cast(int, x),
                                        0x138, 0xf, 0xf, true);    // lane0 <- 0
    return __builtin_bit_cast(float, r);
}
__device__ __forceinline__ float rdlane(float x, int lane) {
    return __builtin_bit_cast(float, __builtin_amdgcn_readlane(__builtin_bit_cast(int, x), lane));
}

// Renorm by the max over the NEEDED lanes only (lane < nlanes). Butterfly via
// __shfl_xor (proven primitive). Masked-out lanes may overflow later: harmless
// (never read, never feed lower lanes, E>0 so no NaN).
__device__ __forceinline__ void renorm(float &A, float &a0, int &off,
                                       int lane, int nlanes) {
    float m = (lane < nlanes) ? A : 0.f;
#pragma unroll
    for (int o = 32; o; o >>= 1) m = fmaxf(m, __shfl_xor(m, o));
    int mb = __builtin_bit_cast(int, m);
    int e = ((mb >> 23) & 0xff) - 127;
    e = (mb & 0x7fffffff) ? e : 0;       // m==0 guard: no rescale
    A  = ldexpf(A,  -e);
    a0 = ldexpf(a0, -e);
    off += e;
}

// ---------------------------------------------------------------------------
// Gather kernel: per preds row [b,t,:]: coalesced float4 read, butterfly lse
// (log2 domain), write LINEAR normalized probs: labelE[pid][t][k], blankE[b][t].
// exp2 runs here (parallel, BW-bound) so the serial recursion has none.
// ---------------------------------------------------------------------------
__global__ __launch_bounds__(256) void gather_kernel(const float* __restrict__ preds,
                                                     const int* __restrict__ text,
                                                     const int* __restrict__ stext,
                                                     float* __restrict__ labelE,
                                                     float* __restrict__ blankE) {
    int gw = (blockIdx.x * blockDim.x + threadIdx.x) >> 6;   // row = b*512+t
    int lane = threadIdx.x & 63;
    if (gw >= BB * TT) return;
    int b = gw >> 9;
    int t = gw & (TT - 1);
    const float* row = preds + (size_t)gw * CC;
    const float4* row4 = (const float4*)row;
    float w[16];
#pragma unroll
    for (int i = 0; i < 4; ++i) {
        int idx = lane + i * 64;
        float4 x = (idx < 250) ? row4[idx] : make_float4(NEGV, NEGV, NEGV, NEGV);
        w[i*4+0] = x.x * LOG2E; w[i*4+1] = x.y * LOG2E;
        w[i*4+2] = x.z * LOG2E; w[i*4+3] = x.w * LOG2E;
    }
    float m = w[0];
#pragma unroll
    for (int i = 1; i < 16; ++i) m = fmaxf(m, w[i]);
#pragma unroll
    for (int off = 32; off; off >>= 1) m = fmaxf(m, __shfl_xor(m, off));
    float s = 0.f;
#pragma unroll
    for (int i = 0; i < 16; ++i) s += exp2f(w[i] - m);
#pragma unroll
    for (int off = 32; off; off >>= 1) s += __shfl_xor(s, off);
    float lse2 = m + log2f(s);               // wave-uniform

    if (lane == 0) blankE[gw] = exp2f(row[0] * LOG2E - lse2);

#pragma unroll
    for (int it = 0; it < 3; ++it) {
        int g = lane + it * 64;
        if (g < 5 * SS) {
            int pp = g >> 5, k = g & 31;
            int cls, pid;
            if (pp == 0) { cls = text[b * SS + k]; pid = b; }
            else { int i = b * COR + (pp - 1); cls = stext[i * SS + k]; pid = BB + i; }
            labelE[((size_t)pid * TT + t) * SS + k] = exp2f(row[cls] * LOG2E - lse2);
        }
    }
}

// ---------------------------------------------------------------------------
// Linear-domain CTC. Lane s owns extended position s+1 (1..64); position 0
// (leading blank) is the wave-uniform scalar a0, injected via the DPP fill.
// Per-step chain: dpp, dpp, cndmask, add, add, mul — zero transcendentals.
//   A'[s] = (A[s] + A[s-1] + use2*A[s-2]) * E[s],  a0' = a0 * E_blank.
// Renorm every 8 steps vs the needed-lane max; exponents accumulate in off.
// loss = -ln2 * (log2(A[2len-1] + A[2len-2]) + off)  (emits pre-normalized).
// ---------------------------------------------------------------------------
__global__ __launch_bounds__(64) void ctc_lin_kernel(const float* __restrict__ labelE,
                                                     const float* __restrict__ blankE,
                                                     const int* __restrict__ text,
                                                     const int* __restrict__ length,
                                                     const int* __restrict__ stext,
                                                     const int* __restrict__ slength,
                                                     float* __restrict__ lm,
                                                     float* __restrict__ ls) {
    const int p = blockIdx.x;
    const int lane = threadIdx.x;

    int b, len;
    const int* tgt;
    if (p < BB) { b = p;        tgt = text  + (size_t)p * SS; len = length[p]; }
    else { int i = p - BB; b = i / COR; tgt = stext + (size_t)i * SS; len = slength[i]; }

    // lane s = position s+1: even s -> label k=s/2; odd s -> blank.
    const bool evenl = !(lane & 1);
    const int k = lane >> 1;
    bool use2 = false;
    if (evenl && lane >= 2) use2 = (tgt[k] != tgt[k - 1]);

    const float* bbase = blankE + (size_t)b * TT;
    const float* basep = evenl ? (labelE + (size_t)p * TT * SS + k) : bbase;
    const int stridep = evenl ? SS : 1;
    const int i2 = 2 * len;                  // needed lanes: [0, i2)

    constexpr int CH = 16;
    constexpr int NCH = TT / CH;             // 32
    float eA[CH], eB[CH], bA[CH], bB[CH];

    auto loadChunk = [&](float (&ee)[CH], float (&bv)[CH], int c) {
#pragma unroll
        for (int j = 0; j < CH; ++j) {
            ee[j] = basep[(size_t)(c * CH + j) * stridep];
            bv[j] = bbase[c * CH + j];
        }
    };

    float A, a0;
    int off = 0;

#define RUN16(EE, BV, START)                                    \
    _Pragma("unroll")                                           \
    for (int j = (START); j < CH; ++j) {                        \
        float p1 = dpp_shr1_fill(A, a0);                        \
        float p2 = dpp_shr1_z(p1);                              \
        float x2 = use2 ? p2 : 0.f;                             \
        A = (A + p1 + x2) * EE[j];                              \
        a0 *= BV[j];                                            \
        if ((j & 7) == 7) renorm(A, a0, off, lane, i2);         \
    }

    // prologue: chunk 0 (t=0 is init), chunk 1 prefetched
    loadChunk(eA, bA, 0);
    loadChunk(eB, bB, 1);
    A  = (lane == 0) ? eA[0] : 0.f;          // alpha0[pos1] = emit(y1)
    a0 = bA[0];                              // alpha0[pos0] = emit(blank)
    RUN16(eA, bA, 1)

    for (int c = 1; c < NCH; c += 2) {
        if (c + 1 < NCH) loadChunk(eA, bA, c + 1);
        RUN16(eB, bB, 0)
        if (c + 1 < NCH) {
            if (c + 2 < NCH) loadChunk(eB, bB, c + 2);
            RUN16(eA, bA, 0)
        }
    }
#undef RUN16

    // final: alpha[2len] at lane 2len-1, alpha[2len-1] at lane 2len-2
    float vhi = rdlane(A, i2 - 1);
    float vlo = rdlane(A, i2 - 2);
    float loss = -LN2 * (log2f(vhi + vlo) + (float)off);

    if (lane == 0) {
        if (p < BB) lm[p] = loss;
        else        ls[p - BB] = loss;
    }
}

// ---------------------------------------------------------------------------
// Fallback path (only if ws too small) — round-3 log-domain kernels (proven).
// ---------------------------------------------------------------------------
__global__ __launch_bounds__(256) void lse_kernel(const float* __restrict__ preds,
                                                  float* __restrict__ lse) {
    int wave = (blockIdx.x * blockDim.x + threadIdx.x) >> 6;
    int lane = threadIdx.x & 63;
    if (wave >= BB * TT) return;
    const float4* row = (const float4*)(preds + (size_t)wave * CC);
    float v[16];
#pragma unroll
    for (int i = 0; i < 4; ++i) {
        int idx = lane + i * 64;
        float4 x = (idx < 250) ? row[idx] : make_float4(NEGV, NEGV, NEGV, NEGV);
        v[i*4+0] = x.x; v[i*4+1] = x.y; v[i*4+2] = x.z; v[i*4+3] = x.w;
    }
    float m = v[0];
#pragma unroll
    for (int i = 1; i < 16; ++i) m = fmaxf(m, v[i]);
#pragma unroll
    for (int off = 32; off; off >>= 1) m = fmaxf(m, __shfl_xor(m, off));
    float s = 0.f;
#pragma unroll
    for (int i = 0; i < 16; ++i) s += exp2f((v[i] - m) * LOG2E);
#pragma unroll
    for (int off = 32; off; off >>= 1) s += __shfl_xor(s, off);
    if (lane == 0) lse[wave] = m + log2f(s) * LN2;
}

__global__ __launch_bounds__(64) void ctc_kernel(const float* __restrict__ preds,
                                                 const float* __restrict__ lse,
                                                 const int* __restrict__ text,
                                                 const int* __restrict__ length,
                                                 const int* __restrict__ stext,
                                                 const int* __restrict__ slength,
                                                 float* __restrict__ lm,
                                                 float* __restrict__ ls) {
    const int p = blockIdx.x;
    const int lane = threadIdx.x;
    int b, len;
    const int* tgt;
    if (p < BB) { b = p;        tgt = text  + (size_t)p * SS; len = length[p]; }
    else { int i = p - BB; b = i / COR; tgt = stext + (size_t)i * SS; len = slength[i]; }
    const int s = lane;
    int cls = (s & 1) ? tgt[(s - 1) >> 1] : 0;
    bool use2 = false;
    if ((s & 1) && s >= 3) use2 = (cls != tgt[(s - 3) >> 1]);
    const float* pcls = preds + (size_t)b * TT * CC + cls;
    const float* lrow = lse + (size_t)b * TT;
    float ksum = 0.f;
#pragma unroll
    for (int i = 0; i < TT / 64; ++i) ksum += lrow[lane + i * 64];
#pragma unroll
    for (int off = 32; off; off >>= 1) ksum += __shfl_xor(ksum, off);
    float a, a64 = NEGV;
    constexpr int CH = 8;
    constexpr int NCH = TT / CH;
    float pvA[CH], pvB[CH];
    auto loadChunk = [&](float (&pv)[CH], int c) {
#pragma unroll
        for (int j = 0; j < CH; ++j) pv[j] = pcls[(size_t)(c * CH + j) * CC];
    };
    auto step = [&](float ev) {
        float p1 = dpp_shr1_fill(a, NEGV);
        float p2 = dpp_shr1_fill(p1, NEGV);
        float x2 = use2 ? p2 : NEGV;
        float m3 = fmaxf(fmaxf(a, p1), x2);
        float ss = exp2f((a - m3) * LOG2E) + exp2f((p1 - m3) * LOG2E) + exp2f((x2 - m3) * LOG2E);
        float a63 = rdlane(a, 63);
        float eb  = rdlane(ev, 0);
        float m2 = fmaxf(a64, a63);
        a64 = m2 + log2f(exp2f((a64 - m2) * LOG2E) + exp2f((a63 - m2) * LOG2E)) * LN2 + eb;
        a = m3 + log2f(ss) * LN2 + ev;
    };
    loadChunk(pvA, 0);
    loadChunk(pvB, 1);
    a = (s < 2) ? pvA[0] : NEGV;
#pragma unroll
    for (int j = 1; j < CH; ++j) step(pvA[j]);
    for (int c = 1; c < NCH; c += 2) {
        if (c + 1 < NCH) loadChunk(pvA, c + 1);
#pragma unroll
        for (int j = 0; j < CH; ++j) step(pvB[j]);
        if (c + 1 < NCH) {
            if (c + 2 < NCH) loadChunk(pvB, c + 2);
#pragma unroll
            for (int j = 0; j < CH; ++j) step(pvA[j]);
        }
    }
    int idx = 2 * len;
    float vhi = (idx < 64) ? rdlane(a, idx) : a64;
    float vlo = rdlane(a, idx - 1);
    float mm = fmaxf(vhi, vlo);
    float lae = mm + log2f(exp2f((vhi - mm) * LOG2E) + exp2f((vlo - mm) * LOG2E)) * LN2;
    float loss = ksum - lae;
    if (lane == 0) {
        if (p < BB) lm[p] = loss;
        else        ls[p - BB] = loss;
    }
}

// ---------------------------------------------------------------------------
// Finalize scalar loss.
// ---------------------------------------------------------------------------
__global__ __launch_bounds__(256) void fin_kernel(const float* __restrict__ lm,
                                                  const float* __restrict__ ls,
                                                  const int* __restrict__ length,
                                                  const int* __restrict__ slength,
                                                  float* __restrict__ out) {
    __shared__ float red[256];
    const int tid = threadIdx.x;

    float mterm = 0.f;
    if (tid < BB) mterm = lm[tid] / (float)length[tid];

    int bb = tid >> 2;
    float conf = expf(-lm[bb]);
    float r = 0.01f + 0.99f * (1.f - conf) * (1.f - conf);
    int sl = slength[tid]; if (sl < 1) sl = 1;
    float sterm = r * ls[tid] / (float)sl;

    red[tid] = mterm; __syncthreads();
    for (int off = 128; off; off >>= 1) {
        if (tid < off) red[tid] += red[tid + off];
        __syncthreads();
    }
    float sum_m = red[0];
    __syncthreads();

    red[tid] = sterm; __syncthreads();
    for (int off = 128; off; off >>= 1) {
        if (tid < off) red[tid] += red[tid + off];
        __syncthreads();
    }
    if (tid == 0)
        out[0] = sum_m / (float)BB + 0.1f * (red[0] / (float)(BB * COR));
}

// ---------------------------------------------------------------------------
extern "C" void kernel_launch(void* const* d_in, const int* in_sizes, int n_in,
                              void* d_out, int out_size, void* d_ws, size_t ws_size,
                              hipStream_t stream) {
    const float* preds   = (const float*)d_in[0];
    const int*   text    = (const int*)d_in[1];
    const int*   length  = (const int*)d_in[2];
    const int*   stext   = (const int*)d_in[3];
    const int*   slength = (const int*)d_in[4];
    float* out = (float*)d_out;

    size_t need = ((size_t)BB * TT + BB + BB * COR + (size_t)NPROB * TT * SS) * sizeof(float);

    if (ws_size >= need) {
        float* blankE = (float*)d_ws;            // 64*512
        float* lm     = blankE + BB * TT;        // 64
        float* ls     = lm + BB;                 // 256
        float* labelE = ls + BB * COR;           // 320*512*32

        gather_kernel<<<(BB * TT) / 4, 256, 0, stream>>>(preds, text, stext, labelE, blankE);
        ctc_lin_kernel<<<NPROB, 64, 0, stream>>>(labelE, blankE, text, length, stext, slength, lm, ls);
        fin_kernel<<<1, 256, 0, stream>>>(lm, ls, length, slength, out);
    } else {
        float* lse = (float*)d_ws;
        float* lm  = lse + BB * TT;
        float* ls  = lm + BB;
        lse_kernel<<<(BB * TT) / 4, 256, 0, stream>>>(preds, lse);
        ctc_kernel<<<NPROB, 64, 0, stream>>>(preds, lse, text, length, stext, slength, lm, ls);
        fin_kernel<<<1, 256, 0, stream>>>(lm, ls, length, slength, out);
    }
}